// Round 8
// baseline (112.601 us; speedup 1.0000x reference)
//
#include <hip/hip_runtime.h>
#include <hip/hip_bf16.h>
#include <math.h>

#define BB 32
#define NP 576
#define WW 32
#define DD 256
// GEMM view: M = 32*576 = 18432, N = 32*32 = 1024, K = 256.
// M is tiled as 144 contiguous 128-row tiles; N-tiles: 8 x 128.
//
// ROUND 8 = MEASUREMENT ROUND #2 (amplified-A). Identical to round 6
// (best: 92.9 us) except norm_cast_kernel is launched FIVE times (idempotent:
// pure function of unchanged inputs -> bit-identical workspace contents).
//   dur_us - 92.9 = 4 x A_warm.
// Round-7 finding: B_warm = 8.7 us (GEMM near structural floor; ~1.1-1.4 PF
// effective, L2-resident operands) and launch gaps must be <= ~2 us (else
// B_warm would be impossibly fast). Budget residual: A + unknown ~= 30 us.
// This round splits that: A_warm ~= 6 -> residual is untouchable harness
// reset traffic -> near-roofline (floor ~= 87-88); A_warm >= 20 -> A is the
// target and gets rewritten next round.

typedef __bf16 bf16x8 __attribute__((ext_vector_type(8)));
typedef float f32x4 __attribute__((ext_vector_type(4)));

__device__ __forceinline__ unsigned short f2bf(float f) {
  unsigned int u = __float_as_uint(f);
  u += 0x7FFFu + ((u >> 16) & 1u);
  return (unsigned short)(u >> 16);
}

// Kernel A: fused L2-normalize + bf16 cast. One wave per row of 256 floats.
__global__ __launch_bounds__(256) void norm_cast_kernel(
    const float* __restrict__ img, const float* __restrict__ con,
    unsigned short* __restrict__ img_bf, unsigned short* __restrict__ con_bf) {
  int row = blockIdx.x * 4 + (threadIdx.x >> 6);
  int lane = threadIdx.x & 63;
  const int n_img = BB * NP;  // 18432 rows
  const float* src;
  unsigned short* dst;
  if (row < n_img) {
    src = img + (size_t)row * DD;
    dst = img_bf + (size_t)row * DD;
  } else {
    int r2 = row - n_img;
    src = con + (size_t)r2 * DD;
    dst = con_bf + (size_t)r2 * DD;
  }
  float4 v = ((const float4*)src)[lane];
  float ss = v.x * v.x + v.y * v.y + v.z * v.z + v.w * v.w;
  #pragma unroll
  for (int off = 1; off < 64; off <<= 1) ss += __shfl_xor(ss, off);
  float inv = 1.0f / fmaxf(sqrtf(ss), 1e-12f);
  ushort4 o;
  o.x = f2bf(v.x * inv);
  o.y = f2bf(v.y * inv);
  o.z = f2bf(v.z * inv);
  o.w = f2bf(v.w * inv);
  ((ushort4*)dst)[lane] = o;
}

// Kernel B: 128x128-tile GEMM (K=256, BK=64) with fused max-over-rows epilogue
// and XCD-chunked tile swizzle (round-6 proven form, unchanged; measured
// B_warm = 8.7 us in round 7).
//   A-frag: lane(q=lane>>4, r=lane&15) holds A[row=r][k=q*8+j]
//   D-frag: lane holds D[row=q*4+reg][col=r]
__global__ __launch_bounds__(256, 3) void gemm_max_kernel(
    const unsigned short* __restrict__ img_bf,  // 18432 x 256
    const unsigned short* __restrict__ con_bf,  // 1024 x 256
    float* __restrict__ P) {                    // [160][1024] partial maxes
  int bx = blockIdx.x;
  // XCD-chunked swizzle: 1152 = 8 x 144 exactly -> bijective.
  int swz = (bx & 7) * 144 + (bx >> 3);
  int bw = swz & 7;    // N-tile 0..7
  int bm = swz >> 3;   // M-tile 0..143
  int R0 = bm * 128;   // global row base (all 128 rows valid)
  int w0 = bw * 128;

  __shared__ __align__(16) unsigned char lds[33 * 1024];
  unsigned char* ldsA = lds;            // 16 KB
  unsigned char* ldsB = lds + 16384;    // 16 KB
  float* sm = (float*)(lds + 32768);    // 2 x 128 floats

  int tid = threadIdx.x;
  int wid = tid >> 6;
  int lane = tid & 63;
  int q = lane >> 4;   // 0..3
  int r = lane & 15;   // 0..15
  int wp = wid >> 1;   // row-half 0..1 (64 rows each)
  int wc = wid & 1;    // col-half 0..1 (64 cols each)

  f32x4 acc[4][4];
  #pragma unroll
  for (int i = 0; i < 4; ++i)
    #pragma unroll
    for (int j = 0; j < 4; ++j) acc[i][j] = (f32x4){0.f, 0.f, 0.f, 0.f};

  for (int kb = 0; kb < 4; ++kb) {
    __syncthreads();  // previous chunk fully consumed before overwrite
    #pragma unroll
    for (int j = 0; j < 4; ++j) {
      int g = j * 256 + wid * 64 + lane;  // 0..1023
      int row = g >> 3;                   // 0..127
      int sl = (g & 7) ^ (row & 7);       // pre-swizzled 16B segment
      const unsigned short* ga = img_bf + (size_t)(R0 + row) * DD + kb * 64 + sl * 8;
      const unsigned short* gb = con_bf + (size_t)(w0 + row) * DD + kb * 64 + sl * 8;
      unsigned char* la = ldsA + (j * 256 + wid * 64) * 16;  // wave-uniform
      unsigned char* lb = ldsB + (j * 256 + wid * 64) * 16;
      __builtin_amdgcn_global_load_lds(
          (const __attribute__((address_space(1))) unsigned int*)ga,
          (__attribute__((address_space(3))) unsigned int*)la, 16, 0, 0);
      __builtin_amdgcn_global_load_lds(
          (const __attribute__((address_space(1))) unsigned int*)gb,
          (__attribute__((address_space(3))) unsigned int*)lb, 16, 0, 0);
    }
    __syncthreads();  // compiler drains vmcnt(0) before the barrier
    #pragma unroll
    for (int kk = 0; kk < 2; ++kk) {
      bf16x8 af[4], bfr[4];
      int sw = ((((kk << 2) | q) ^ (r & 7)) << 4);
      #pragma unroll
      for (int pi = 0; pi < 4; ++pi) {
        int arow = wp * 64 + pi * 16 + r;
        af[pi] = *(const bf16x8*)(ldsA + arow * 128 + sw);
      }
      #pragma unroll
      for (int wj = 0; wj < 4; ++wj) {
        int brow = wc * 64 + wj * 16 + r;
        bfr[wj] = *(const bf16x8*)(ldsB + brow * 128 + sw);
      }
      #pragma unroll
      for (int pi = 0; pi < 4; ++pi)
        #pragma unroll
        for (int wj = 0; wj < 4; ++wj)
          acc[pi][wj] =
              __builtin_amdgcn_mfma_f32_16x16x32_bf16(af[pi], bfr[wj], acc[pi][wj], 0, 0, 0);
    }
  }

  // Epilogue: max over this wave's 64 rows for each of its 64 cols.
  float mxw[4];
  #pragma unroll
  for (int wj = 0; wj < 4; ++wj) {
    float v = -1e30f;
    #pragma unroll
    for (int pi = 0; pi < 4; ++pi) {
      v = fmaxf(v, fmaxf(fmaxf(acc[pi][wj][0], acc[pi][wj][1]),
                         fmaxf(acc[pi][wj][2], acc[pi][wj][3])));
    }
    v = fmaxf(v, __shfl_xor(v, 16));
    v = fmaxf(v, __shfl_xor(v, 32));
    mxw[wj] = v;
  }
  __syncthreads();
  if (lane < 16) {
    #pragma unroll
    for (int wj = 0; wj < 4; ++wj)
      sm[wp * 128 + wc * 64 + wj * 16 + lane] = mxw[wj];
  }
  __syncthreads();
  if (tid < 128) {
    int i0 = (2 * bm) / 9;                 // image of rows [R0, R0+64)
    int slot = bm - (9 * i0) / 2;          // tile slot within image i0 (0..4)
    bool crossing = ((2 * bm) % 9) == 8;   // boundary at local row 64
    float vlo = sm[tid];                   // rows 0..63  -> image i0
    float vhi = sm[128 + tid];             // rows 64..127 -> i0 or i0+1
    if (crossing) {
      P[(size_t)(i0 * 5 + slot) * 1024 + w0 + tid] = vlo;       // slot==4 here
      P[(size_t)((i0 + 1) * 5) * 1024 + w0 + tid] = vhi;        // slot 0 of i0+1
    } else {
      P[(size_t)(i0 * 5 + slot) * 1024 + w0 + tid] = fmaxf(vlo, vhi);
    }
  }
}

// Kernel C: reduce partial maxes over the 5 tile-slots of each image, masked
// mean over valid concepts -> sims. (Round-1 proven form.)
__global__ __launch_bounds__(256) void reduce_kernel(
    const float* __restrict__ P, const int* __restrict__ lengths,
    float* __restrict__ sims) {
  int pair = blockIdx.x * 4 + (threadIdx.x >> 6);  // 0..1023
  int lane = threadIdx.x & 63;
  int m = pair >> 5;
  int c = pair & 31;
  int w = lane & 31;
  const float* base = P + (size_t)(m * 5) * 1024 + c * 32 + w;
  float v = base[0];
  v = fmaxf(v, base[1024]);
  v = fmaxf(v, base[2048]);
  v = fmaxf(v, base[3072]);
  v = fmaxf(v, base[4096]);
  int len = lengths[c];
  float contrib = (w < len) ? v : 0.0f;
  #pragma unroll
  for (int off = 1; off < 32; off <<= 1) contrib += __shfl_xor(contrib, off);
  if (lane == 0) sims[pair] = contrib / (float)len;
}

// Kernel D: fold 1024 sims into the SigLIP-style loss.
__global__ __launch_bounds__(256) void loss_kernel(
    const float* __restrict__ sims, const float* __restrict__ lscale,
    const float* __restrict__ lbias, float* __restrict__ out) {
  float tt = expf(fminf(fmaxf(lscale[0], -10.0f), 10.0f));
  float bias = lbias[0];
  int tid = threadIdx.x;
  float acc = 0.0f;
  for (int p = tid; p < BB * BB; p += 256) {
    int mm = p >> 5;
    int cc = p & 31;
    float lg = fminf(fmaxf(tt * sims[p] + bias, -50.0f), 50.0f);
    float x = (mm == cc) ? lg : -lg;
    float ls = (x >= 0.0f) ? -log1pf(expf(-x)) : (x - log1pf(expf(x)));
    acc += ls;
  }
  #pragma unroll
  for (int off = 1; off < 64; off <<= 1) acc += __shfl_xor(acc, off);
  __shared__ float s[4];
  if ((tid & 63) == 0) s[tid >> 6] = acc;
  __syncthreads();
  if (tid == 0) out[0] = -(s[0] + s[1] + s[2] + s[3]) / (float)(BB * BB);
}

extern "C" void kernel_launch(void* const* d_in, const int* in_sizes, int n_in,
                              void* d_out, int out_size, void* d_ws, size_t ws_size,
                              hipStream_t stream) {
  const float* img = (const float*)d_in[0];  // (32, 576, 256) f32
  const float* con = (const float*)d_in[1];  // (32, 32, 256) f32
  const int* lens = (const int*)d_in[2];     // (32,) i32
  const float* lsc = (const float*)d_in[3];  // (1,)
  const float* lbi = (const float*)d_in[4];  // (1,)

  unsigned short* img_bf = (unsigned short*)d_ws;              // 18432*256 bf16
  unsigned short* con_bf = img_bf + (size_t)BB * NP * DD;      // 1024*256 bf16
  float* P = (float*)(con_bf + (size_t)BB * WW * DD);          // 160*1024 f32
  float* sims = P + (size_t)160 * 1024;                        // 1024 f32

  const int nblkA = (BB * NP + BB * WW) / 4;
  // MEASUREMENT: 5 identical launches of A (idempotent).
  // dur_us - 92.9 = 4 x A_warm.
  norm_cast_kernel<<<nblkA, 256, 0, stream>>>(img, con, img_bf, con_bf);
  norm_cast_kernel<<<nblkA, 256, 0, stream>>>(img, con, img_bf, con_bf);
  norm_cast_kernel<<<nblkA, 256, 0, stream>>>(img, con, img_bf, con_bf);
  norm_cast_kernel<<<nblkA, 256, 0, stream>>>(img, con, img_bf, con_bf);
  norm_cast_kernel<<<nblkA, 256, 0, stream>>>(img, con, img_bf, con_bf);
  gemm_max_kernel<<<144 * 8, 256, 0, stream>>>(img_bf, con_bf, P);
  reduce_kernel<<<256, 256, 0, stream>>>(P, lens, sims);
  loss_kernel<<<1, 256, 0, stream>>>(sims, lsc, lbi, (float*)d_out);
}

// Round 9
// 92.943 us; speedup vs baseline: 1.2115x; 1.2115x over previous
//
#include <hip/hip_runtime.h>
#include <hip/hip_bf16.h>
#include <math.h>

#define BB 32
#define NP 576
#define WW 32
#define DD 256
// GEMM view: M = 32*576 = 18432, N = 32*32 = 1024, K = 256.
// M is tiled as 144 contiguous 128-row tiles (image boundaries handled in the
// epilogue: gcd(128,576)=64 so a crossing tile always splits at local row 64,
// i.e. exactly at the wp wave split). N-tiles: 8 x 128.
//
// FINAL KERNEL (= round-6 optimum, 92.9 us). Session budget, all measured:
//   fill (harness re-poison)  ~45 us   untouchable (75% HBM peak)
//   harness residual + gaps   ~23 us   untouchable (gaps <=2 us, proven R7)
//   A norm+cast                4.9 us  measured (R8 5x-launch); at mem floor
//   B gemm+max                 8.7 us  measured (R7 2x-launch); ~1.1 PF eff.
//   C+D                        ~3 us   fusion measured WORSE (R3 +9, R4 +3.7)
// Wins kept: XCD-chunked tile swizzle (-2.2 us, R6), global_load_lds staging
// + pre-swizzled source (R0), separate small kernels (R1 form).
// Falsified en route: 7 us/launch gap model (R2/R7), BM=192 under (256,3)
// VGPR cap (R2 spill), threadfence-based fusion (R3 L2-writeback storm),
// double-buffered BK=32 prefetch (R5 null: B is locality-, not
// latency-limited), pure-BW theory of B (R6: swizzle won 2.2, not 12).

typedef __bf16 bf16x8 __attribute__((ext_vector_type(8)));
typedef float f32x4 __attribute__((ext_vector_type(4)));

__device__ __forceinline__ unsigned short f2bf(float f) {
  unsigned int u = __float_as_uint(f);
  u += 0x7FFFu + ((u >> 16) & 1u);
  return (unsigned short)(u >> 16);
}

// Kernel A: fused L2-normalize + bf16 cast. One wave per row of 256 floats.
// Measured 4.9 us (R8), below the naive 6.3 us floor (L3-warm inputs).
__global__ __launch_bounds__(256) void norm_cast_kernel(
    const float* __restrict__ img, const float* __restrict__ con,
    unsigned short* __restrict__ img_bf, unsigned short* __restrict__ con_bf) {
  int row = blockIdx.x * 4 + (threadIdx.x >> 6);
  int lane = threadIdx.x & 63;
  const int n_img = BB * NP;  // 18432 rows
  const float* src;
  unsigned short* dst;
  if (row < n_img) {
    src = img + (size_t)row * DD;
    dst = img_bf + (size_t)row * DD;
  } else {
    int r2 = row - n_img;
    src = con + (size_t)r2 * DD;
    dst = con_bf + (size_t)r2 * DD;
  }
  float4 v = ((const float4*)src)[lane];
  float ss = v.x * v.x + v.y * v.y + v.z * v.z + v.w * v.w;
  #pragma unroll
  for (int off = 1; off < 64; off <<= 1) ss += __shfl_xor(ss, off);
  float inv = 1.0f / fmaxf(sqrtf(ss), 1e-12f);
  ushort4 o;
  o.x = f2bf(v.x * inv);
  o.y = f2bf(v.y * inv);
  o.z = f2bf(v.z * inv);
  o.w = f2bf(v.w * inv);
  ((ushort4*)dst)[lane] = o;
}

// Kernel B: 128x128-tile GEMM (K=256, BK=64) with fused max-over-rows epilogue
// and XCD-chunked tile swizzle. Measured 8.7 us warm (R7) ~= 1.1 PF effective
// (L2-resident operands). Staging: global_load_lds width=16, linear LDS dest,
// XOR swizzle applied to the PRE-SWIZZLED GLOBAL source segment (m173) so the
// ds_read_b128 fragment reads are bank-conflict-free.
//   A-frag: lane(q=lane>>4, r=lane&15) holds A[row=r][k=q*8+j]
//   D-frag: lane holds D[row=q*4+reg][col=r]
__global__ __launch_bounds__(256, 3) void gemm_max_kernel(
    const unsigned short* __restrict__ img_bf,  // 18432 x 256
    const unsigned short* __restrict__ con_bf,  // 1024 x 256
    float* __restrict__ P) {                    // [160][1024] partial maxes
  int bx = blockIdx.x;
  // XCD-chunked swizzle: 1152 = 8 x 144 exactly -> bijective. XCD bx%8 owns
  // contiguous tile range; 8 consecutive tiles share one A-panel on-XCD
  // (working set 1.18 MB A + 0.5 MB B fits the 4 MB per-XCD L2). -2.2 us (R6).
  int swz = (bx & 7) * 144 + (bx >> 3);
  int bw = swz & 7;    // N-tile 0..7
  int bm = swz >> 3;   // M-tile 0..143
  int R0 = bm * 128;   // global row base (all 128 rows valid)
  int w0 = bw * 128;

  __shared__ __align__(16) unsigned char lds[33 * 1024];
  unsigned char* ldsA = lds;            // 16 KB
  unsigned char* ldsB = lds + 16384;    // 16 KB
  float* sm = (float*)(lds + 32768);    // 2 x 128 floats

  int tid = threadIdx.x;
  int wid = tid >> 6;
  int lane = tid & 63;
  int q = lane >> 4;   // 0..3
  int r = lane & 15;   // 0..15
  int wp = wid >> 1;   // row-half 0..1 (64 rows each)
  int wc = wid & 1;    // col-half 0..1 (64 cols each)

  f32x4 acc[4][4];
  #pragma unroll
  for (int i = 0; i < 4; ++i)
    #pragma unroll
    for (int j = 0; j < 4; ++j) acc[i][j] = (f32x4){0.f, 0.f, 0.f, 0.f};

  for (int kb = 0; kb < 4; ++kb) {
    __syncthreads();  // previous chunk fully consumed before overwrite
    #pragma unroll
    for (int j = 0; j < 4; ++j) {
      int g = j * 256 + wid * 64 + lane;  // 0..1023
      int row = g >> 3;                   // 0..127
      int sl = (g & 7) ^ (row & 7);       // pre-swizzled 16B segment
      const unsigned short* ga = img_bf + (size_t)(R0 + row) * DD + kb * 64 + sl * 8;
      const unsigned short* gb = con_bf + (size_t)(w0 + row) * DD + kb * 64 + sl * 8;
      unsigned char* la = ldsA + (j * 256 + wid * 64) * 16;  // wave-uniform
      unsigned char* lb = ldsB + (j * 256 + wid * 64) * 16;
      __builtin_amdgcn_global_load_lds(
          (const __attribute__((address_space(1))) unsigned int*)ga,
          (__attribute__((address_space(3))) unsigned int*)la, 16, 0, 0);
      __builtin_amdgcn_global_load_lds(
          (const __attribute__((address_space(1))) unsigned int*)gb,
          (__attribute__((address_space(3))) unsigned int*)lb, 16, 0, 0);
    }
    __syncthreads();  // compiler drains vmcnt(0) before the barrier
    #pragma unroll
    for (int kk = 0; kk < 2; ++kk) {
      bf16x8 af[4], bfr[4];
      int sw = ((((kk << 2) | q) ^ (r & 7)) << 4);
      #pragma unroll
      for (int pi = 0; pi < 4; ++pi) {
        int arow = wp * 64 + pi * 16 + r;
        af[pi] = *(const bf16x8*)(ldsA + arow * 128 + sw);
      }
      #pragma unroll
      for (int wj = 0; wj < 4; ++wj) {
        int brow = wc * 64 + wj * 16 + r;
        bfr[wj] = *(const bf16x8*)(ldsB + brow * 128 + sw);
      }
      #pragma unroll
      for (int pi = 0; pi < 4; ++pi)
        #pragma unroll
        for (int wj = 0; wj < 4; ++wj)
          acc[pi][wj] =
              __builtin_amdgcn_mfma_f32_16x16x32_bf16(af[pi], bfr[wj], acc[pi][wj], 0, 0, 0);
    }
  }

  // Epilogue: max over this wave's 64 rows for each of its 64 cols.
  float mxw[4];
  #pragma unroll
  for (int wj = 0; wj < 4; ++wj) {
    float v = -1e30f;
    #pragma unroll
    for (int pi = 0; pi < 4; ++pi) {
      v = fmaxf(v, fmaxf(fmaxf(acc[pi][wj][0], acc[pi][wj][1]),
                         fmaxf(acc[pi][wj][2], acc[pi][wj][3])));
    }
    v = fmaxf(v, __shfl_xor(v, 16));
    v = fmaxf(v, __shfl_xor(v, 32));
    mxw[wj] = v;
  }
  __syncthreads();
  if (lane < 16) {
    #pragma unroll
    for (int wj = 0; wj < 4; ++wj)
      sm[wp * 128 + wc * 64 + wj * 16 + lane] = mxw[wj];
  }
  __syncthreads();
  if (tid < 128) {
    int i0 = (2 * bm) / 9;                 // image of rows [R0, R0+64)
    int slot = bm - (9 * i0) / 2;          // tile slot within image i0 (0..4)
    bool crossing = ((2 * bm) % 9) == 8;   // boundary at local row 64
    float vlo = sm[tid];                   // rows 0..63  -> image i0
    float vhi = sm[128 + tid];             // rows 64..127 -> i0 or i0+1
    if (crossing) {
      P[(size_t)(i0 * 5 + slot) * 1024 + w0 + tid] = vlo;       // slot==4 here
      P[(size_t)((i0 + 1) * 5) * 1024 + w0 + tid] = vhi;        // slot 0 of i0+1
    } else {
      P[(size_t)(i0 * 5 + slot) * 1024 + w0 + tid] = fmaxf(vlo, vhi);
    }
  }
}

// Kernel C: reduce partial maxes over the 5 tile-slots of each image, masked
// mean over valid concepts -> sims. Kept separate: both fusion variants with
// D measured worse (R3 +9 us fence storm, R4 +3.7 us fence-free).
__global__ __launch_bounds__(256) void reduce_kernel(
    const float* __restrict__ P, const int* __restrict__ lengths,
    float* __restrict__ sims) {
  int pair = blockIdx.x * 4 + (threadIdx.x >> 6);  // 0..1023
  int lane = threadIdx.x & 63;
  int m = pair >> 5;
  int c = pair & 31;
  int w = lane & 31;
  const float* base = P + (size_t)(m * 5) * 1024 + c * 32 + w;
  float v = base[0];
  v = fmaxf(v, base[1024]);
  v = fmaxf(v, base[2048]);
  v = fmaxf(v, base[3072]);
  v = fmaxf(v, base[4096]);
  int len = lengths[c];
  float contrib = (w < len) ? v : 0.0f;
  #pragma unroll
  for (int off = 1; off < 32; off <<= 1) contrib += __shfl_xor(contrib, off);
  if (lane == 0) sims[pair] = contrib / (float)len;
}

// Kernel D: fold 1024 sims into the SigLIP-style loss.
__global__ __launch_bounds__(256) void loss_kernel(
    const float* __restrict__ sims, const float* __restrict__ lscale,
    const float* __restrict__ lbias, float* __restrict__ out) {
  float tt = expf(fminf(fmaxf(lscale[0], -10.0f), 10.0f));
  float bias = lbias[0];
  int tid = threadIdx.x;
  float acc = 0.0f;
  for (int p = tid; p < BB * BB; p += 256) {
    int mm = p >> 5;
    int cc = p & 31;
    float lg = fminf(fmaxf(tt * sims[p] + bias, -50.0f), 50.0f);
    float x = (mm == cc) ? lg : -lg;
    float ls = (x >= 0.0f) ? -log1pf(expf(-x)) : (x - log1pf(expf(x)));
    acc += ls;
  }
  #pragma unroll
  for (int off = 1; off < 64; off <<= 1) acc += __shfl_xor(acc, off);
  __shared__ float s[4];
  if ((tid & 63) == 0) s[tid >> 6] = acc;
  __syncthreads();
  if (tid == 0) out[0] = -(s[0] + s[1] + s[2] + s[3]) / (float)(BB * BB);
}

extern "C" void kernel_launch(void* const* d_in, const int* in_sizes, int n_in,
                              void* d_out, int out_size, void* d_ws, size_t ws_size,
                              hipStream_t stream) {
  const float* img = (const float*)d_in[0];  // (32, 576, 256) f32
  const float* con = (const float*)d_in[1];  // (32, 32, 256) f32
  const int* lens = (const int*)d_in[2];     // (32,) i32
  const float* lsc = (const float*)d_in[3];  // (1,)
  const float* lbi = (const float*)d_in[4];  // (1,)

  unsigned short* img_bf = (unsigned short*)d_ws;              // 18432*256 bf16
  unsigned short* con_bf = img_bf + (size_t)BB * NP * DD;      // 1024*256 bf16
  float* P = (float*)(con_bf + (size_t)BB * WW * DD);          // 160*1024 f32
  float* sims = P + (size_t)160 * 1024;                        // 1024 f32

  norm_cast_kernel<<<(BB * NP + BB * WW) / 4, 256, 0, stream>>>(img, con, img_bf, con_bf);
  gemm_max_kernel<<<144 * 8, 256, 0, stream>>>(img_bf, con_bf, P);
  reduce_kernel<<<256, 256, 0, stream>>>(P, lens, sims);
  loss_kernel<<<1, 256, 0, stream>>>(sims, lsc, lbi, (float*)d_out);
}